// Round 1
// baseline (4271.109 us; speedup 1.0000x reference)
//
#include <hip/hip_runtime.h>
#include <math.h>

// SLSTM: T=1024, B=256, C=14, H=128, 4H=512, NC=7. All fp32.
//
// Decomposition (recurrence is independent per batch element; layer-2's input
// matmul has no recurrence once spk1 is known):
//   R1: layer-1 recurrence, 1 block per batch element, W_ih1+W_hh1 in VGPRs
//       (thread j owns gate row j). Writes packed spike bits (4 MB).
//   G2: Z2[t,b,:] = spk1[t,b,:] @ W_ih2^T + (b_ih2+b_hh2)  -- parallel GEMM,
//       same register-row structure, chunked over t to fit ws.
//   R2: layer-2 recurrence, W_hh2 in VGPRs, Z2 streamed+prefetched.
//   FC: out = (sum_t mem2 / T) @ fc_w^T + fc_b.

#define T_STEPS 1024
#define BATCH   256
#define H       128
#define G4      512
#define NC      7

__device__ __forceinline__ float sigf(float v) { return 1.0f / (1.0f + expf(-v)); }

// ---------------------------------------------------------------- layer 1
__global__ __launch_bounds__(512, 2) void r1_kernel(
    const float* __restrict__ x,      // [T,B,14]
    const float* __restrict__ Wih1,   // [512,14]
    const float* __restrict__ Whh1,   // [512,128]
    const float* __restrict__ bih1,
    const float* __restrict__ bhh1,
    const float* __restrict__ thr1p,
    unsigned long long* __restrict__ spk)  // [T,B,2] packed bits
{
  const int b = blockIdx.x;
  const int j = threadIdx.x;   // gate row 0..511

  __shared__ __align__(16) float xbuf[T_STEPS * 16];  // x padded 14->16, 64 KB
  __shared__ __align__(16) float membuf[H];
  __shared__ float gbuf[G4];

  float wih[16];
#pragma unroll
  for (int c = 0; c < 14; ++c) wih[c] = Wih1[j * 14 + c];
  wih[14] = 0.f; wih[15] = 0.f;

  float whh[128];
#pragma unroll
  for (int k = 0; k < 128; k += 4) {
    float4 v = *(const float4*)(Whh1 + j * 128 + k);
    whh[k] = v.x; whh[k + 1] = v.y; whh[k + 2] = v.z; whh[k + 3] = v.w;
  }
  const float bias = bih1[j] + bhh1[j];
  const float thr  = thr1p[0];

  // stage this batch element's whole input sequence into LDS (one-time)
  for (int m = j; m < T_STEPS * 16; m += 512) {
    int t = m >> 4, c = m & 15;
    xbuf[m] = (c < 14) ? x[(t * BATCH + b) * 14 + c] : 0.f;
  }

  float syn = 0.f, mem = 0.f;  // state owned by threads 0..127 (h == j)
  if (j < H) membuf[j] = 0.f;
  __syncthreads();

  for (int t = 0; t < T_STEPS; ++t) {
    float a0 = 0.f, a1 = 0.f, a2 = 0.f, a3 = 0.f;
    const float4* xr = (const float4*)&xbuf[t << 4];
    float4 v;
    v = xr[0]; a0 += wih[0] * v.x + wih[1] * v.y + wih[2] * v.z + wih[3] * v.w;
    v = xr[1]; a1 += wih[4] * v.x + wih[5] * v.y + wih[6] * v.z + wih[7] * v.w;
    v = xr[2]; a2 += wih[8] * v.x + wih[9] * v.y + wih[10] * v.z + wih[11] * v.w;
    v = xr[3]; a3 += wih[12] * v.x + wih[13] * v.y;

#pragma unroll
    for (int k = 0; k < 128; k += 16) {
      float4 m0 = *(const float4*)&membuf[k];
      float4 m1 = *(const float4*)&membuf[k + 4];
      float4 m2 = *(const float4*)&membuf[k + 8];
      float4 m3 = *(const float4*)&membuf[k + 12];
      a0 += whh[k] * m0.x + whh[k + 1] * m0.y + whh[k + 2] * m0.z + whh[k + 3] * m0.w;
      a1 += whh[k + 4] * m1.x + whh[k + 5] * m1.y + whh[k + 6] * m1.z + whh[k + 7] * m1.w;
      a2 += whh[k + 8] * m2.x + whh[k + 9] * m2.y + whh[k + 10] * m2.z + whh[k + 11] * m2.w;
      a3 += whh[k + 12] * m3.x + whh[k + 13] * m3.y + whh[k + 14] * m3.z + whh[k + 15] * m3.w;
    }
    gbuf[j] = bias + (a0 + a1) + (a2 + a3);
    __syncthreads();

    bool sp = false;
    if (j < H) {
      float gi = gbuf[j], gf = gbuf[j + 128], gg = gbuf[j + 256], go = gbuf[j + 384];
      float si = sigf(gi), sf = sigf(gf), so = sigf(go);
      syn = sf * syn + si * tanhf(gg);
      float reset = (mem - thr > 0.f) ? 1.f : 0.f;  // pre-update mem, detached
      mem = so * tanhf(syn) - reset * thr;
      membuf[j] = mem;
      sp = (mem - thr) > 0.f;
    }
    unsigned long long mask = __ballot(sp);
    if (j < H && (j & 63) == 0)
      spk[(size_t)(t * BATCH + b) * 2 + (j >> 6)] = mask;
    __syncthreads();
  }
}

// ------------------------------------------- layer-2 input GEMM (chunked)
__global__ __launch_bounds__(512, 2) void g2_kernel(
    const unsigned long long* __restrict__ spk,  // [T,B,2]
    const float* __restrict__ Wih2,              // [512,128]
    const float* __restrict__ bih2,
    const float* __restrict__ bhh2,
    float* __restrict__ z2,                      // [ch,B,512]
    int t0, int rows_per_blk)
{
  const int j = threadIdx.x;
  float w[128];
#pragma unroll
  for (int k = 0; k < 128; k += 4) {
    float4 v = *(const float4*)(Wih2 + j * 128 + k);
    w[k] = v.x; w[k + 1] = v.y; w[k + 2] = v.z; w[k + 3] = v.w;
  }
  const float bias = bih2[j] + bhh2[j];
  __shared__ __align__(16) float sbuf[H];

  const int r0 = blockIdx.x * rows_per_blk;
  for (int r = r0; r < r0 + rows_per_blk; ++r) {
    if (j < H) {
      unsigned long long m = spk[(size_t)(t0 * BATCH + r) * 2 + (j >> 6)];
      sbuf[j] = ((m >> (j & 63)) & 1ull) ? 1.f : 0.f;
    }
    __syncthreads();
    float a0 = 0.f, a1 = 0.f, a2 = 0.f, a3 = 0.f;
#pragma unroll
    for (int k = 0; k < 128; k += 16) {
      float4 m0 = *(const float4*)&sbuf[k];
      float4 m1 = *(const float4*)&sbuf[k + 4];
      float4 m2 = *(const float4*)&sbuf[k + 8];
      float4 m3 = *(const float4*)&sbuf[k + 12];
      a0 += w[k] * m0.x + w[k + 1] * m0.y + w[k + 2] * m0.z + w[k + 3] * m0.w;
      a1 += w[k + 4] * m1.x + w[k + 5] * m1.y + w[k + 6] * m1.z + w[k + 7] * m1.w;
      a2 += w[k + 8] * m2.x + w[k + 9] * m2.y + w[k + 10] * m2.z + w[k + 11] * m2.w;
      a3 += w[k + 12] * m3.x + w[k + 13] * m3.y + w[k + 14] * m3.z + w[k + 15] * m3.w;
    }
    z2[(size_t)r * G4 + j] = bias + (a0 + a1) + (a2 + a3);
    __syncthreads();
  }
}

// ---------------------------------------------------------------- layer 2
__global__ __launch_bounds__(512, 2) void r2_kernel(
    const float* __restrict__ z2,     // [ch,B,512]
    const float* __restrict__ Whh2,   // [512,128]
    const float* __restrict__ thr2p,
    float* __restrict__ state,        // [3][B][H] : syn2, mem2, sum(mem2)
    int ch, int first)
{
  const int b = blockIdx.x;
  const int j = threadIdx.x;
  float w[128];
#pragma unroll
  for (int k = 0; k < 128; k += 4) {
    float4 v = *(const float4*)(Whh2 + j * 128 + k);
    w[k] = v.x; w[k + 1] = v.y; w[k + 2] = v.z; w[k + 3] = v.w;
  }
  const float thr = thr2p[0];
  __shared__ __align__(16) float membuf[H];
  __shared__ float gbuf[G4];

  float syn = 0.f, mem = 0.f, sum = 0.f;
  if (j < H) {
    if (!first) {
      syn = state[b * H + j];
      mem = state[BATCH * H + b * H + j];
      sum = state[2 * BATCH * H + b * H + j];
    }
    membuf[j] = mem;
  }
  __syncthreads();

  float znext = z2[(size_t)b * G4 + j];
  for (int tl = 0; tl < ch; ++tl) {
    float z = znext;
    if (tl + 1 < ch) znext = z2[(size_t)((tl + 1) * BATCH + b) * G4 + j];
    float a0 = 0.f, a1 = 0.f, a2 = 0.f, a3 = 0.f;
#pragma unroll
    for (int k = 0; k < 128; k += 16) {
      float4 m0 = *(const float4*)&membuf[k];
      float4 m1 = *(const float4*)&membuf[k + 4];
      float4 m2 = *(const float4*)&membuf[k + 8];
      float4 m3 = *(const float4*)&membuf[k + 12];
      a0 += w[k] * m0.x + w[k + 1] * m0.y + w[k + 2] * m0.z + w[k + 3] * m0.w;
      a1 += w[k + 4] * m1.x + w[k + 5] * m1.y + w[k + 6] * m1.z + w[k + 7] * m1.w;
      a2 += w[k + 8] * m2.x + w[k + 9] * m2.y + w[k + 10] * m2.z + w[k + 11] * m2.w;
      a3 += w[k + 12] * m3.x + w[k + 13] * m3.y + w[k + 14] * m3.z + w[k + 15] * m3.w;
    }
    gbuf[j] = z + (a0 + a1) + (a2 + a3);
    __syncthreads();
    if (j < H) {
      float gi = gbuf[j], gf = gbuf[j + 128], gg = gbuf[j + 256], go = gbuf[j + 384];
      float si = sigf(gi), sf = sigf(gf), so = sigf(go);
      syn = sf * syn + si * tanhf(gg);
      float reset = (mem - thr > 0.f) ? 1.f : 0.f;
      mem = so * tanhf(syn) - reset * thr;
      sum += mem;
      membuf[j] = mem;
    }
    __syncthreads();
  }
  if (j < H) {
    state[b * H + j] = syn;
    state[BATCH * H + b * H + j] = mem;
    state[2 * BATCH * H + b * H + j] = sum;
  }
}

// ---------------------------------------------------------------- readout
__global__ void fc_kernel(const float* __restrict__ sumbuf,  // [B,H] sum over t
                          const float* __restrict__ fcw,     // [NC,H]
                          const float* __restrict__ fcb,     // [NC]
                          float* __restrict__ out)           // [B,NC]
{
  int g = blockIdx.x * blockDim.x + threadIdx.x;
  if (g >= BATCH * NC) return;
  int b = g / NC, c = g % NC;
  const float* s  = sumbuf + b * H;
  const float* wr = fcw + c * H;
  float acc = 0.f;
#pragma unroll
  for (int h = 0; h < H; h += 4) {
    float4 sv = *(const float4*)(s + h);
    float4 wv = *(const float4*)(wr + h);
    acc += sv.x * wv.x + sv.y * wv.y + sv.z * wv.z + sv.w * wv.w;
  }
  out[g] = fcb[c] + acc * (1.f / 1024.f);
}

extern "C" void kernel_launch(void* const* d_in, const int* in_sizes, int n_in,
                              void* d_out, int out_size, void* d_ws, size_t ws_size,
                              hipStream_t stream)
{
  (void)in_sizes; (void)n_in; (void)out_size;
  const float* x    = (const float*)d_in[0];
  const float* Wih1 = (const float*)d_in[1];
  const float* Whh1 = (const float*)d_in[2];
  const float* bih1 = (const float*)d_in[3];
  const float* bhh1 = (const float*)d_in[4];
  const float* thr1 = (const float*)d_in[5];
  const float* Wih2 = (const float*)d_in[6];
  const float* Whh2 = (const float*)d_in[7];
  const float* bih2 = (const float*)d_in[8];
  const float* bhh2 = (const float*)d_in[9];
  const float* thr2 = (const float*)d_in[10];
  const float* fcw  = (const float*)d_in[11];
  const float* fcb  = (const float*)d_in[12];

  char* ws = (char*)d_ws;
  unsigned long long* spk = (unsigned long long*)ws;            // 4 MB
  float* state = (float*)(ws + (4u << 20));                     // 384 KB
  float* z2    = (float*)(ws + (4u << 20) + (1u << 19));

  // pick largest power-of-two time-chunk whose Z2 buffer fits the workspace
  size_t hdr = (4u << 20) + (1u << 19);
  size_t avail = (ws_size > hdr) ? (ws_size - hdr) : 0;
  int ch = 1024;
  while (ch > 8 && (size_t)ch * BATCH * G4 * sizeof(float) > avail) ch >>= 1;

  r1_kernel<<<256, 512, 0, stream>>>(x, Wih1, Whh1, bih1, bhh1, thr1, spk);

  int first = 1;
  for (int t0 = 0; t0 < T_STEPS; t0 += ch) {
    g2_kernel<<<256, 512, 0, stream>>>(spk, Wih2, bih2, bhh2, z2, t0, ch);
    r2_kernel<<<256, 512, 0, stream>>>(z2, Whh2, thr2, state, ch, first);
    first = 0;
  }

  fc_kernel<<<(BATCH * NC + 255) / 256, 256, 0, stream>>>(
      state + 2 * BATCH * H, fcw, fcb, (float*)d_out);
}

// Round 2
// 3643.981 us; speedup vs baseline: 1.1721x; 1.1721x over previous
//
#include <hip/hip_runtime.h>
#include <math.h>

// SLSTM: T=1024, B=256, C=14, H=128, 4H=512, NC=7. All fp32.
//
// Round 2: LDS-broadcast -> v_readlane broadcast (VALU) everywhere.
//   R1: layer-1 recurrence, 1 block/batch. W_ih1+W_hh1 in VGPRs (thread j owns
//       gate row j). mem[] broadcast via readlane; activations redundant in all
//       waves. Writes packed spike bits.
//   G2: Z2 = spk1 @ W_ih2^T + biases. No LDS, no barriers; spike row bits ->
//       {0,1} floats per lane, readlane broadcast.
//   R2: layer-2 recurrence, W_hh2 in VGPRs, Z2 prefetched from global.
//   FC: out = (sum_t mem2 / T) @ fc_w^T + fc_b.

#define T_STEPS 1024
#define BATCH   256
#define H       128
#define G4      512
#define NC      7

__device__ __forceinline__ float sigf(float v) { return 1.0f / (1.0f + expf(-v)); }

__device__ __forceinline__ float bcast(float v, int lane) {
  return __int_as_float(__builtin_amdgcn_readlane(__float_as_int(v), lane));
}

// ---------------------------------------------------------------- layer 1
__global__ __launch_bounds__(512, 2) void r1_kernel(
    const float* __restrict__ x,      // [T,B,14]
    const float* __restrict__ Wih1,   // [512,14]
    const float* __restrict__ Whh1,   // [512,128]
    const float* __restrict__ bih1,
    const float* __restrict__ bhh1,
    const float* __restrict__ thr1p,
    unsigned long long* __restrict__ spk)  // [T,B,2] packed bits
{
  const int b    = blockIdx.x;
  const int j    = threadIdx.x;       // gate row 0..511
  const int lane = j & 63;
  const int wav  = j >> 6;
  const int par  = wav & 1;           // which half of h this wave owns
  const int h    = j & 127;           // = (par<<6) | lane

  __shared__ __align__(16) float xbuf[T_STEPS * 16];  // x padded 14->16, 64 KB
  __shared__ float gbuf[G4];
  __shared__ float membuf[H];

  float wih[16];
#pragma unroll
  for (int c = 0; c < 14; ++c) wih[c] = Wih1[j * 14 + c];
  wih[14] = 0.f; wih[15] = 0.f;

  float whh[128];
#pragma unroll
  for (int k = 0; k < 128; k += 4) {
    float4 v = *(const float4*)(Whh1 + j * 128 + k);
    whh[k] = v.x; whh[k + 1] = v.y; whh[k + 2] = v.z; whh[k + 3] = v.w;
  }
  const float bias = bih1[j] + bhh1[j];
  const float thr  = thr1p[0];

  // stage this batch element's whole input sequence into LDS (one-time)
  for (int m = j; m < T_STEPS * 16; m += 512) {
    int t = m >> 4, c = m & 15;
    xbuf[m] = (c < 14) ? x[(t * BATCH + b) * 14 + c] : 0.f;
  }

  float syn = 0.f, mem = 0.f;   // state for this wave's h (redundant x4)
  float vOwn = 0.f, vOth = 0.f; // mem[(par<<6)+lane], mem[((1-par)<<6)+lane]
  __syncthreads();

  for (int t = 0; t < T_STEPS; ++t) {
    float a0 = 0.f, a1 = 0.f, a2 = 0.f, a3 = 0.f;
    const float4* xr = (const float4*)&xbuf[t << 4];
    float4 v;
    v = xr[0]; a0 += wih[0] * v.x + wih[1] * v.y + wih[2] * v.z + wih[3] * v.w;
    v = xr[1]; a1 += wih[4] * v.x + wih[5] * v.y + wih[6] * v.z + wih[7] * v.w;
    v = xr[2]; a2 += wih[8] * v.x + wih[9] * v.y + wih[10] * v.z + wih[11] * v.w;
    v = xr[3]; a3 += wih[12] * v.x + wih[13] * v.y;

    const float vLow  = par ? vOth : vOwn;  // lane L holds mem[L]
    const float vHigh = par ? vOwn : vOth;  // lane L holds mem[64+L]
#pragma unroll
    for (int k = 0; k < 64; k += 4) {
      a0 += whh[k + 0] * bcast(vLow, k + 0);
      a1 += whh[k + 1] * bcast(vLow, k + 1);
      a2 += whh[k + 2] * bcast(vLow, k + 2);
      a3 += whh[k + 3] * bcast(vLow, k + 3);
    }
#pragma unroll
    for (int k = 0; k < 64; k += 4) {
      a0 += whh[64 + k + 0] * bcast(vHigh, k + 0);
      a1 += whh[64 + k + 1] * bcast(vHigh, k + 1);
      a2 += whh[64 + k + 2] * bcast(vHigh, k + 2);
      a3 += whh[64 + k + 3] * bcast(vHigh, k + 3);
    }
    gbuf[j] = bias + (a0 + a1) + (a2 + a3);
    __syncthreads();

    // redundant activation: every wave updates state for its own h
    float gi = gbuf[h], gf = gbuf[h + 128], gg = gbuf[h + 256], go = gbuf[h + 384];
    float si = sigf(gi), sf = sigf(gf), so = sigf(go);
    syn = sf * syn + si * tanhf(gg);
    float reset = (mem - thr > 0.f) ? 1.f : 0.f;  // pre-update mem, detached
    mem = so * tanhf(syn) - reset * thr;
    bool sp = (mem - thr) > 0.f;
    unsigned long long mask = __ballot(sp);
    if (wav < 2) {
      membuf[h] = mem;
      if (lane == 0) spk[(size_t)(t * BATCH + b) * 2 + par] = mask;
    }
    __syncthreads();
    vOwn = mem;
    vOth = membuf[((1 - par) << 6) | lane];
  }
}

// ------------------------------------------- layer-2 input GEMM (chunked)
__global__ __launch_bounds__(512, 2) void g2_kernel(
    const unsigned long long* __restrict__ spk,  // [T,B,2]
    const float* __restrict__ Wih2,              // [512,128]
    const float* __restrict__ bih2,
    const float* __restrict__ bhh2,
    float* __restrict__ z2,                      // [ch,B,512]
    int t0, int rows_per_blk)
{
  const int j    = threadIdx.x;
  const int lane = j & 63;
  float w[128];
#pragma unroll
  for (int k = 0; k < 128; k += 4) {
    float4 v = *(const float4*)(Wih2 + j * 128 + k);
    w[k] = v.x; w[k + 1] = v.y; w[k + 2] = v.z; w[k + 3] = v.w;
  }
  const float bias = bih2[j] + bhh2[j];

  const int r0   = blockIdx.x * rows_per_blk;
  const int rEnd = r0 + rows_per_blk;
  ulonglong2 nxt = *(const ulonglong2*)&spk[(size_t)(t0 * BATCH + r0) * 2];
  for (int r = r0; r < rEnd; ++r) {
    ulonglong2 cur = nxt;
    if (r + 1 < rEnd)
      nxt = *(const ulonglong2*)&spk[(size_t)(t0 * BATCH + r + 1) * 2];
    const float vLow  = ((cur.x >> lane) & 1ull) ? 1.f : 0.f;  // s[lane]
    const float vHigh = ((cur.y >> lane) & 1ull) ? 1.f : 0.f;  // s[64+lane]

    float a0 = 0.f, a1 = 0.f, a2 = 0.f, a3 = 0.f;
#pragma unroll
    for (int k = 0; k < 64; k += 4) {
      a0 += w[k + 0] * bcast(vLow, k + 0);
      a1 += w[k + 1] * bcast(vLow, k + 1);
      a2 += w[k + 2] * bcast(vLow, k + 2);
      a3 += w[k + 3] * bcast(vLow, k + 3);
    }
#pragma unroll
    for (int k = 0; k < 64; k += 4) {
      a0 += w[64 + k + 0] * bcast(vHigh, k + 0);
      a1 += w[64 + k + 1] * bcast(vHigh, k + 1);
      a2 += w[64 + k + 2] * bcast(vHigh, k + 2);
      a3 += w[64 + k + 3] * bcast(vHigh, k + 3);
    }
    z2[(size_t)r * G4 + j] = bias + (a0 + a1) + (a2 + a3);
  }
}

// ---------------------------------------------------------------- layer 2
__global__ __launch_bounds__(512, 2) void r2_kernel(
    const float* __restrict__ z2,     // [ch,B,512]
    const float* __restrict__ Whh2,   // [512,128]
    const float* __restrict__ thr2p,
    float* __restrict__ state,        // [3][B][H] : syn2, mem2, sum(mem2)
    int ch, int first)
{
  const int b    = blockIdx.x;
  const int j    = threadIdx.x;
  const int lane = j & 63;
  const int wav  = j >> 6;
  const int par  = wav & 1;
  const int h    = j & 127;

  float w[128];
#pragma unroll
  for (int k = 0; k < 128; k += 4) {
    float4 v = *(const float4*)(Whh2 + j * 128 + k);
    w[k] = v.x; w[k + 1] = v.y; w[k + 2] = v.z; w[k + 3] = v.w;
  }
  const float thr = thr2p[0];
  __shared__ float gbuf[G4];
  __shared__ float membuf[H];

  float syn = 0.f, mem = 0.f, sum = 0.f;
  if (!first) {
    syn = state[b * H + h];
    mem = state[BATCH * H + b * H + h];
    sum = state[2 * BATCH * H + b * H + h];
  }
  float vOwn = mem;
  if (wav < 2) membuf[h] = mem;
  __syncthreads();
  float vOth = membuf[((1 - par) << 6) | lane];

  float znext = z2[(size_t)b * G4 + j];
  for (int tl = 0; tl < ch; ++tl) {
    float z = znext;
    if (tl + 1 < ch) znext = z2[(size_t)((tl + 1) * BATCH + b) * G4 + j];

    const float vLow  = par ? vOth : vOwn;
    const float vHigh = par ? vOwn : vOth;
    float a0 = 0.f, a1 = 0.f, a2 = 0.f, a3 = 0.f;
#pragma unroll
    for (int k = 0; k < 64; k += 4) {
      a0 += w[k + 0] * bcast(vLow, k + 0);
      a1 += w[k + 1] * bcast(vLow, k + 1);
      a2 += w[k + 2] * bcast(vLow, k + 2);
      a3 += w[k + 3] * bcast(vLow, k + 3);
    }
#pragma unroll
    for (int k = 0; k < 64; k += 4) {
      a0 += w[64 + k + 0] * bcast(vHigh, k + 0);
      a1 += w[64 + k + 1] * bcast(vHigh, k + 1);
      a2 += w[64 + k + 2] * bcast(vHigh, k + 2);
      a3 += w[64 + k + 3] * bcast(vHigh, k + 3);
    }
    gbuf[j] = z + (a0 + a1) + (a2 + a3);
    __syncthreads();

    float gi = gbuf[h], gf = gbuf[h + 128], gg = gbuf[h + 256], go = gbuf[h + 384];
    float si = sigf(gi), sf = sigf(gf), so = sigf(go);
    syn = sf * syn + si * tanhf(gg);
    float reset = (mem - thr > 0.f) ? 1.f : 0.f;
    mem = so * tanhf(syn) - reset * thr;
    sum += mem;
    if (wav < 2) membuf[h] = mem;
    __syncthreads();
    vOwn = mem;
    vOth = membuf[((1 - par) << 6) | lane];
  }
  if (wav < 2) {
    state[b * H + h] = syn;
    state[BATCH * H + b * H + h] = mem;
    state[2 * BATCH * H + b * H + h] = sum;
  }
}

// ---------------------------------------------------------------- readout
__global__ void fc_kernel(const float* __restrict__ sumbuf,  // [B,H] sum over t
                          const float* __restrict__ fcw,     // [NC,H]
                          const float* __restrict__ fcb,     // [NC]
                          float* __restrict__ out)           // [B,NC]
{
  int g = blockIdx.x * blockDim.x + threadIdx.x;
  if (g >= BATCH * NC) return;
  int b = g / NC, c = g % NC;
  const float* s  = sumbuf + b * H;
  const float* wr = fcw + c * H;
  float acc = 0.f;
#pragma unroll
  for (int hh = 0; hh < H; hh += 4) {
    float4 sv = *(const float4*)(s + hh);
    float4 wv = *(const float4*)(wr + hh);
    acc += sv.x * wv.x + sv.y * wv.y + sv.z * wv.z + sv.w * wv.w;
  }
  out[g] = fcb[c] + acc * (1.f / 1024.f);
}

extern "C" void kernel_launch(void* const* d_in, const int* in_sizes, int n_in,
                              void* d_out, int out_size, void* d_ws, size_t ws_size,
                              hipStream_t stream)
{
  (void)in_sizes; (void)n_in; (void)out_size;
  const float* x    = (const float*)d_in[0];
  const float* Wih1 = (const float*)d_in[1];
  const float* Whh1 = (const float*)d_in[2];
  const float* bih1 = (const float*)d_in[3];
  const float* bhh1 = (const float*)d_in[4];
  const float* thr1 = (const float*)d_in[5];
  const float* Wih2 = (const float*)d_in[6];
  const float* Whh2 = (const float*)d_in[7];
  const float* bih2 = (const float*)d_in[8];
  const float* bhh2 = (const float*)d_in[9];
  const float* thr2 = (const float*)d_in[10];
  const float* fcw  = (const float*)d_in[11];
  const float* fcb  = (const float*)d_in[12];

  char* ws = (char*)d_ws;
  unsigned long long* spk = (unsigned long long*)ws;            // 4 MB
  float* state = (float*)(ws + (4u << 20));                     // 384 KB
  float* z2    = (float*)(ws + (4u << 20) + (1u << 19));

  // pick largest power-of-two time-chunk whose Z2 buffer fits the workspace
  size_t hdr = (4u << 20) + (1u << 19);
  size_t avail = (ws_size > hdr) ? (ws_size - hdr) : 0;
  int ch = 1024;
  while (ch > 8 && (size_t)ch * BATCH * G4 * sizeof(float) > avail) ch >>= 1;

  r1_kernel<<<256, 512, 0, stream>>>(x, Wih1, Whh1, bih1, bhh1, thr1, spk);

  int first = 1;
  for (int t0 = 0; t0 < T_STEPS; t0 += ch) {
    g2_kernel<<<256, 512, 0, stream>>>(spk, Wih2, bih2, bhh2, z2, t0, ch);
    r2_kernel<<<256, 512, 0, stream>>>(z2, Whh2, thr2, state, ch, first);
    first = 0;
  }

  fc_kernel<<<(BATCH * NC + 255) / 256, 256, 0, stream>>>(
      state + 2 * BATCH * H, fcw, fcb, (float*)d_out);
}